// Round 6
// baseline (314.487 us; speedup 1.0000x reference)
//
#include <hip/hip_runtime.h>

typedef unsigned short u16;
typedef unsigned int u32;
using frag8 = __attribute__((ext_vector_type(8))) short;   // 8 x bf16 (4 VGPRs)
using f32x4 = __attribute__((ext_vector_type(4))) float;   // 16x16 MFMA accumulator

// ---------- helpers ----------
__device__ __forceinline__ u16 f2bf(float f) {
  union { float f; u32 u; } x;
  x.f = f;
  u32 r = (x.u + 0x7fffu + ((x.u >> 16) & 1u)) >> 16;  // RNE
  return (u16)r;
}

// Stage a 128x64 bf16 tile (row-major, k contiguous) global -> LDS via async
// global_load_lds, width 16B. 256 threads, 4 issues each. LDS dest must be
// wave-uniform base + lane*16 (hardware constraint) so the LDS image is
// lane-ordered; we XOR-swizzle WHICH global chunk each lane fetches
// (colc ^ row&7) to break the 128B-row-stride bank aliasing. frag_read64
// applies the same XOR to find its data.
__device__ __forceinline__ void stage_tile64(const u16* g, int ld, u16* lds, int tid) {
  const int wv = tid >> 6;
#pragma unroll
  for (int i = 0; i < 4; ++i) {
    const int c = i * 256 + tid;              // 16B chunk index, 1024 total
    const int row = c >> 3;                   // 8 chunks per 64-elem row
    const int colc = (c & 7) ^ (row & 7);     // swizzled source chunk
    __builtin_amdgcn_global_load_lds(
        (const __attribute__((address_space(1))) void*)(g + (size_t)row * ld + colc * 8),
        (__attribute__((address_space(3))) void*)(lds + (size_t)(i * 256 + wv * 64) * 8),
        16, 0, 0);
  }
}

// Reg-staged f32 -> bf16 version of the same LDS image (for x, killing the
// separate prep pass over 64 MB). ds_write has per-lane address freedom, so
// the XOR swizzle is applied directly on the store side. Split into
// load-half (issue early, longest latency) and store-half (cvt + ds_write).
__device__ __forceinline__ void stage_x_load(const float* g, int ld, float4* v, int tid) {
#pragma unroll
  for (int i = 0; i < 4; ++i) {
    const int c = i * 256 + tid;
    const int row = c >> 3;
    const int colc = (c & 7) ^ (row & 7);
    const float4* s = (const float4*)(g + (size_t)row * ld + colc * 8);
    v[2 * i]     = s[0];
    v[2 * i + 1] = s[1];
  }
}
__device__ __forceinline__ void stage_x_store(const float4* v, u16* lds, int tid) {
#pragma unroll
  for (int i = 0; i < 4; ++i) {
    const int c = i * 256 + tid;
    const float4 a = v[2 * i], b = v[2 * i + 1];
    frag8 o;
    o[0] = (short)f2bf(a.x); o[1] = (short)f2bf(a.y);
    o[2] = (short)f2bf(a.z); o[3] = (short)f2bf(a.w);
    o[4] = (short)f2bf(b.x); o[5] = (short)f2bf(b.y);
    o[6] = (short)f2bf(b.z); o[7] = (short)f2bf(b.w);
    *(frag8*)&lds[(size_t)c * 8] = o;   // ds_write_b128 at chunk c*16B
  }
}

// 16x16x32 A/B fragment from a swizzled 128x64 tile; kk selects k-half (0/1).
__device__ __forceinline__ frag8 frag_read64(const u16* lds, int row, int kk, int quad) {
  const int cc = (kk * 4 + quad) ^ (row & 7);
  return *(const frag8*)&lds[row * 64 + cc * 8];
}

// ---------- small prep: bf16 casts of Wq, Wk, Wv + exp(pos_bias) ----------
// x is no longer pre-cast (qkvu reg-stages it). 64 B/thread.
// block ranges: [0,64) Wq | [64,128) Wk | [128,192) Wv | [192,448) exp(pb)
__global__ void prep_kernel(const float* __restrict__ Wq, const float* __restrict__ Wk,
                            const float* __restrict__ Wv, const float* __restrict__ pb,
                            u16* __restrict__ wqb, u16* __restrict__ wkb,
                            u16* __restrict__ wvb, u16* __restrict__ ewb) {
  const int blk = blockIdx.x;
  const float* src;
  u16* dst;
  int base;
  bool ex = false;
  if (blk < 64)       { src = Wq; dst = wqb; base = blk; }
  else if (blk < 128) { src = Wk; dst = wkb; base = blk - 64; }
  else if (blk < 192) { src = Wv; dst = wvb; base = blk - 128; }
  else                { src = pb; dst = ewb; base = blk - 192; ex = true; }
#pragma unroll
  for (int j = 0; j < 4; ++j) {
    const int i = base * 1024 + j * 256 + threadIdx.x;
    float4 v = ((const float4*)src)[i];
    ushort4 o;
    if (ex) {
      o.x = f2bf(__expf(v.x)); o.y = f2bf(__expf(v.y));
      o.z = f2bf(__expf(v.z)); o.w = f2bf(__expf(v.w));
    } else {
      o.x = f2bf(v.x); o.y = f2bf(v.y); o.z = f2bf(v.z); o.w = f2bf(v.w);
    }
    ((ushort4*)dst)[i] = o;
  }
}

// ---------- unified QKV projection (x cast fused in) ----------
// One block computes q-tile [128t x 128d], ek/ekv tiles [128d x 128s] from a
// SINGLE staging of the x panel (read directly in f32, cast in-register):
// per K-step: issue 8 x-f32 loads -> issue 12 W gload_lds (stay in flight
// past the x-register wait, counted vmcnt) -> cvt + swizzled ds_write ->
// sync -> 96 MFMA. Operand-swap gives q (C[t][d]) and k/v (C[d][s]) from
// the same LDS fragments.
__global__ __launch_bounds__(256, 2) void qkvu_kernel(const float* __restrict__ xf,
                                                      const u16* __restrict__ wqb,
                                                      const u16* __restrict__ wkb,
                                                      const u16* __restrict__ wvb,
                                                      const float* __restrict__ bq,
                                                      const float* __restrict__ bk,
                                                      const float* __restrict__ bv,
                                                      float* __restrict__ out,
                                                      u16* __restrict__ ekT,
                                                      u16* __restrict__ ekvT) {
  __shared__ __align__(16) u16 Xs[128 * 64];
  __shared__ __align__(16) u16 Ws_q[128 * 64];
  __shared__ __align__(16) u16 Ws_k[128 * 64];
  __shared__ __align__(16) u16 Ws_v[128 * 64];
  const int tid = threadIdx.x;
  const int lane = tid & 63, wv = tid >> 6;
  const int wmx = (wv & 1) * 64;   // x-row (t/s) offset of wave
  const int wnw = (wv >> 1) * 64;  // w-row (d) offset of wave
  const int fr = lane & 15, quad = lane >> 4;
  const int n0 = (blockIdx.x & 3) * 128;   // d-block over 512
  const int mt = blockIdx.x >> 2;          // m-tile over 32768/128 = 256
  const int m0 = mt * 128;                 // global x row
  const int b  = mt >> 3;                  // batch
  const int s0 = (mt & 7) * 128;           // seq pos within batch

  f32x4 accq[4][4] = {}, acck[4][4] = {}, accv[4][4] = {};
  for (int k0 = 0; k0 < 512; k0 += 64) {
    float4 v[8];
    stage_x_load(xf + (size_t)m0 * 512 + k0, 512, v, tid);       // f32 loads first
    stage_tile64(wqb + (size_t)n0 * 512 + k0, 512, Ws_q, tid);   // DMA stays in flight
    stage_tile64(wkb + (size_t)n0 * 512 + k0, 512, Ws_k, tid);
    stage_tile64(wvb + (size_t)n0 * 512 + k0, 512, Ws_v, tid);
    stage_x_store(v, Xs, tid);                                   // cvt + swizzled ds_write
    __syncthreads();
#pragma unroll
    for (int kk = 0; kk < 2; ++kk) {
      frag8 xa[4], wb[4];
#pragma unroll
      for (int i = 0; i < 4; ++i) xa[i] = frag_read64(Xs, wmx + i * 16 + fr, kk, quad);
      // ---- Q: C[t][d] ----
#pragma unroll
      for (int i = 0; i < 4; ++i) wb[i] = frag_read64(Ws_q, wnw + i * 16 + fr, kk, quad);
#pragma unroll
      for (int mi = 0; mi < 4; ++mi)
#pragma unroll
        for (int ni = 0; ni < 4; ++ni)
          accq[mi][ni] = __builtin_amdgcn_mfma_f32_16x16x32_bf16(xa[mi], wb[ni], accq[mi][ni], 0, 0, 0);
      // ---- K: C[d][s] ----
#pragma unroll
      for (int i = 0; i < 4; ++i) wb[i] = frag_read64(Ws_k, wnw + i * 16 + fr, kk, quad);
#pragma unroll
      for (int ni = 0; ni < 4; ++ni)
#pragma unroll
        for (int mi = 0; mi < 4; ++mi)
          acck[ni][mi] = __builtin_amdgcn_mfma_f32_16x16x32_bf16(wb[ni], xa[mi], acck[ni][mi], 0, 0, 0);
      // ---- V: C[d][s] ----
#pragma unroll
      for (int i = 0; i < 4; ++i) wb[i] = frag_read64(Ws_v, wnw + i * 16 + fr, kk, quad);
#pragma unroll
      for (int ni = 0; ni < 4; ++ni)
#pragma unroll
        for (int mi = 0; mi < 4; ++mi)
          accv[ni][mi] = __builtin_amdgcn_mfma_f32_16x16x32_bf16(wb[ni], xa[mi], accv[ni][mi], 0, 0, 0);
    }
    __syncthreads();
  }
  // ---- Q epilogue: out = sigmoid(q + bq), f32 ----
#pragma unroll
  for (int mi = 0; mi < 4; ++mi)
#pragma unroll
    for (int ni = 0; ni < 4; ++ni) {
      const int col = n0 + wnw + ni * 16 + fr;
      const float bqv = bq[col];
#pragma unroll
      for (int r = 0; r < 4; ++r) {
        const int row = m0 + wmx + mi * 16 + quad * 4 + r;
        const float qv = accq[mi][ni][r] + bqv;
        out[(size_t)row * 512 + col] = 1.0f / (1.0f + __expf(-qv));
      }
    }
  // ---- KV epilogue: ekT/ekvT [b][d][s] bf16 ----
#pragma unroll
  for (int ni = 0; ni < 4; ++ni)
#pragma unroll
    for (int r = 0; r < 4; ++r) {
      const int d = n0 + wnw + ni * 16 + quad * 4 + r;
      const float bkv = bk[d], bvv = bv[d];
#pragma unroll
      for (int mi = 0; mi < 4; ++mi) {
        const int s = s0 + wmx + mi * 16 + fr;
        const float ek = __expf(acck[ni][mi][r] + bkv);
        const float vvv = accv[ni][mi][r] + bvv;
        const size_t idx = ((size_t)b * 512 + d) * 1024 + s;
        ekT[idx]  = f2bf(ek);
        ekvT[idx] = f2bf(ek * vvv);
      }
    }
}

// ---------- AFT mixing: out = sigq * (EW@ekv) / (EW@ek), per batch ----------
// Proven R0 structure (74.6 us, MfmaUtil 37.9): 128x128 tile, 2-barrier
// K-loop, ~3 blocks/CU for implicit inter-block overlap. The 4-phase
// lockstep variants (R2/R3) measured WORSE (80-83 us) - coarse phase-split
// without the full m201 interleave is the m196 anti-pattern.
__global__ __launch_bounds__(256, 2) void aft_kernel(const u16* __restrict__ ew,
                                                     const u16* __restrict__ ekT,
                                                     const u16* __restrict__ ekvT,
                                                     float* __restrict__ out) {
  __shared__ __align__(16) u16 As[128 * 64];
  __shared__ __align__(16) u16 B1[128 * 64];
  __shared__ __align__(16) u16 B2[128 * 64];
  const int tid = threadIdx.x;
  const int lane = tid & 63, wv = tid >> 6;
  const int wm = (wv & 1) * 64, wn = (wv >> 1) * 64;
  const int fr = lane & 15, quad = lane >> 4;
  const int d0 = blockIdx.x * 128;   // n: feature dim (512)
  const int t0 = blockIdx.y * 128;   // m: target pos (1024)
  const int b  = blockIdx.z;
  f32x4 accn[4][4] = {}, accd[4][4] = {};
  for (int k0 = 0; k0 < 1024; k0 += 64) {
    stage_tile64(ew + (size_t)t0 * 1024 + k0, 1024, As, tid);
    stage_tile64(ekvT + ((size_t)b * 512 + d0) * 1024 + k0, 1024, B1, tid);
    stage_tile64(ekT + ((size_t)b * 512 + d0) * 1024 + k0, 1024, B2, tid);
    __syncthreads();
#pragma unroll
    for (int kk = 0; kk < 2; ++kk) {
      frag8 a[4], b1[4], b2[4];
#pragma unroll
      for (int i = 0; i < 4; ++i) {
        a[i]  = frag_read64(As, wm + i * 16 + fr, kk, quad);
        b1[i] = frag_read64(B1, wn + i * 16 + fr, kk, quad);
        b2[i] = frag_read64(B2, wn + i * 16 + fr, kk, quad);
      }
#pragma unroll
      for (int mi = 0; mi < 4; ++mi)
#pragma unroll
        for (int ni = 0; ni < 4; ++ni) {
          accn[mi][ni] = __builtin_amdgcn_mfma_f32_16x16x32_bf16(a[mi], b1[ni], accn[mi][ni], 0, 0, 0);
          accd[mi][ni] = __builtin_amdgcn_mfma_f32_16x16x32_bf16(a[mi], b2[ni], accd[mi][ni], 0, 0, 0);
        }
    }
    __syncthreads();
  }
#pragma unroll
  for (int mi = 0; mi < 4; ++mi)
#pragma unroll
    for (int ni = 0; ni < 4; ++ni)
#pragma unroll
      for (int r = 0; r < 4; ++r) {
        const int t = t0 + wm + mi * 16 + quad * 4 + r;
        const int d = d0 + wn + ni * 16 + fr;
        const size_t idx = ((size_t)b * 1024 + t) * 512 + d;
        const float sq = out[idx];                    // sigmoid(q) from qkvu_kernel
        out[idx] = sq * accn[mi][ni][r] / accd[mi][ni][r];
      }
}

// ---------- launch ----------
// Workspace layout (bytes) — xb slot now unused (x is read f32 directly):
//   wqb  bf16[512][512]        @ 33554432
//   wkb                        @ 34078720
//   wvb                        @ 34603008
//   ewb  bf16[1024][1024]      @ 35127296   (2 MB)
//   ekT  bf16[32][512][1024]   @ 37224448   (32 MB)
//   ekvT bf16[32][512][1024]   @ 70778880   (32 MB)
// sigmoid(q) lives in d_out (read-then-overwrite in aft_kernel).
extern "C" void kernel_launch(void* const* d_in, const int* in_sizes, int n_in,
                              void* d_out, int out_size, void* d_ws, size_t ws_size,
                              hipStream_t stream) {
  const float* x  = (const float*)d_in[0];
  const float* Wq = (const float*)d_in[1];
  const float* bq = (const float*)d_in[2];
  const float* Wk = (const float*)d_in[3];
  const float* bk = (const float*)d_in[4];
  const float* Wv = (const float*)d_in[5];
  const float* bv = (const float*)d_in[6];
  const float* pb = (const float*)d_in[7];
  float* out = (float*)d_out;
  char* ws = (char*)d_ws;
  u16* wqb  = (u16*)(ws + 33554432);
  u16* wkb  = (u16*)(ws + 34078720);
  u16* wvb  = (u16*)(ws + 34603008);
  u16* ewb  = (u16*)(ws + 35127296);
  u16* ekT  = (u16*)(ws + 37224448);
  u16* ekvT = (u16*)(ws + 70778880);

  prep_kernel<<<448, 256, 0, stream>>>(Wq, Wk, Wv, pb, wqb, wkb, wvb, ewb);
  qkvu_kernel<<<1024, 256, 0, stream>>>(x, wqb, wkb, wvb, bq, bk, bv, out, ekT, ekvT);
  aft_kernel<<<dim3(4, 8, 32), 256, 0, stream>>>(ewb, ekT, ekvT, out);
}

// Round 7
// 255.103 us; speedup vs baseline: 1.2328x; 1.2328x over previous
//
#include <hip/hip_runtime.h>

typedef unsigned short u16;
typedef unsigned int u32;
using frag8 = __attribute__((ext_vector_type(8))) short;   // 8 x bf16 (4 VGPRs)
using f32x4 = __attribute__((ext_vector_type(4))) float;   // 16x16 MFMA accumulator

// ---------- helpers ----------
__device__ __forceinline__ u16 f2bf(float f) {
  union { float f; u32 u; } x;
  x.f = f;
  u32 r = (x.u + 0x7fffu + ((x.u >> 16) & 1u)) >> 16;  // RNE
  return (u16)r;
}

// Stage a 128x64 bf16 tile (row-major, k contiguous) global -> LDS via async
// global_load_lds, width 16B. 256 threads, 4 issues each. LDS dest must be
// wave-uniform base + lane*16 (hardware constraint) so the LDS image is
// lane-ordered; we XOR-swizzle WHICH global chunk each lane fetches
// (colc ^ row&7) to break the 128B-row-stride bank aliasing. frag_read64
// applies the same XOR to find its data.
__device__ __forceinline__ void stage_tile64(const u16* g, int ld, u16* lds, int tid) {
  const int wv = tid >> 6;
#pragma unroll
  for (int i = 0; i < 4; ++i) {
    const int c = i * 256 + tid;              // 16B chunk index, 1024 total
    const int row = c >> 3;                   // 8 chunks per 64-elem row
    const int colc = (c & 7) ^ (row & 7);     // swizzled source chunk
    __builtin_amdgcn_global_load_lds(
        (const __attribute__((address_space(1))) void*)(g + (size_t)row * ld + colc * 8),
        (__attribute__((address_space(3))) void*)(lds + (size_t)(i * 256 + wv * 64) * 8),
        16, 0, 0);
  }
}

// 16x16x32 A/B fragment from a swizzled 128x64 tile; kk selects k-half (0/1).
__device__ __forceinline__ frag8 frag_read64(const u16* lds, int row, int kk, int quad) {
  const int cc = (kk * 4 + quad) ^ (row & 7);
  return *(const frag8*)&lds[row * 64 + cc * 8];
}

// ---------- fused prep: bf16 casts of x, Wq, Wk, Wv + exp(pos_bias) ----------
// 64 B/thread: each block covers 1024 float4s (4 per thread).
// block ranges: [0,4096) x | [4096,4160) Wq | [4160,4224) Wk | [4224,4288) Wv
// | [4288,4544) exp(pos_bias)
__global__ void prep_kernel(const float* __restrict__ x, const float* __restrict__ Wq,
                            const float* __restrict__ Wk, const float* __restrict__ Wv,
                            const float* __restrict__ pb, u16* __restrict__ xb,
                            u16* __restrict__ wqb, u16* __restrict__ wkb,
                            u16* __restrict__ wvb, u16* __restrict__ ewb) {
  const int blk = blockIdx.x;
  const float* src;
  u16* dst;
  int base;
  bool ex = false;
  if (blk < 4096)      { src = x;  dst = xb;  base = blk; }
  else if (blk < 4160) { src = Wq; dst = wqb; base = blk - 4096; }
  else if (blk < 4224) { src = Wk; dst = wkb; base = blk - 4160; }
  else if (blk < 4288) { src = Wv; dst = wvb; base = blk - 4224; }
  else                 { src = pb; dst = ewb; base = blk - 4288; ex = true; }
#pragma unroll
  for (int j = 0; j < 4; ++j) {
    const int i = base * 1024 + j * 256 + threadIdx.x;
    float4 v = ((const float4*)src)[i];
    ushort4 o;
    if (ex) {
      o.x = f2bf(__expf(v.x)); o.y = f2bf(__expf(v.y));
      o.z = f2bf(__expf(v.z)); o.w = f2bf(__expf(v.w));
    } else {
      o.x = f2bf(v.x); o.y = f2bf(v.y); o.z = f2bf(v.z); o.w = f2bf(v.w);
    }
    ((ushort4*)dst)[i] = o;
  }
}

// ---------- unified QKV projection ----------
// One block computes q-tile [128t x 128d], ek/ekv tiles [128d x 128s] from a
// SINGLE staging of the x panel: per K-step stage {x, Wq, Wk, Wv} (64 KB) and
// issue 96 MFMA. The operand-swap trick reuses the same LDS fragments:
//   q:  mfma(x_frag,  w_frag) -> C[t][d]
//   kv: mfma(w_frag,  x_frag) -> C[d][s]   (A/B frag layouts are identical)
// Measured (R5): 75.5 us, MfmaUtil 28, FETCH 70.8 MB, 0 bank conflicts.
// R6's fused-x-cast variant regressed to 160 us (f32 x re-read x4 d-blocks,
// FETCH 145 MB) - x must stay pre-cast bf16.
__global__ __launch_bounds__(256, 2) void qkvu_kernel(const u16* __restrict__ xb,
                                                      const u16* __restrict__ wqb,
                                                      const u16* __restrict__ wkb,
                                                      const u16* __restrict__ wvb,
                                                      const float* __restrict__ bq,
                                                      const float* __restrict__ bk,
                                                      const float* __restrict__ bv,
                                                      float* __restrict__ out,
                                                      u16* __restrict__ ekT,
                                                      u16* __restrict__ ekvT) {
  __shared__ __align__(16) u16 Xs[128 * 64];
  __shared__ __align__(16) u16 Ws_q[128 * 64];
  __shared__ __align__(16) u16 Ws_k[128 * 64];
  __shared__ __align__(16) u16 Ws_v[128 * 64];
  const int tid = threadIdx.x;
  const int lane = tid & 63, wv = tid >> 6;
  const int wmx = (wv & 1) * 64;   // x-row (t/s) offset of wave
  const int wnw = (wv >> 1) * 64;  // w-row (d) offset of wave
  const int fr = lane & 15, quad = lane >> 4;
  const int n0 = (blockIdx.x & 3) * 128;   // d-block over 512
  const int mt = blockIdx.x >> 2;          // m-tile over 32768/128 = 256
  const int m0 = mt * 128;                 // global x row
  const int b  = mt >> 3;                  // batch
  const int s0 = (mt & 7) * 128;           // seq pos within batch

  f32x4 accq[4][4] = {}, acck[4][4] = {}, accv[4][4] = {};
  for (int k0 = 0; k0 < 512; k0 += 64) {
    stage_tile64(xb + (size_t)m0 * 512 + k0, 512, Xs, tid);
    stage_tile64(wqb + (size_t)n0 * 512 + k0, 512, Ws_q, tid);
    stage_tile64(wkb + (size_t)n0 * 512 + k0, 512, Ws_k, tid);
    stage_tile64(wvb + (size_t)n0 * 512 + k0, 512, Ws_v, tid);
    __syncthreads();
#pragma unroll
    for (int kk = 0; kk < 2; ++kk) {
      frag8 xa[4], wb[4];
#pragma unroll
      for (int i = 0; i < 4; ++i) xa[i] = frag_read64(Xs, wmx + i * 16 + fr, kk, quad);
      // ---- Q: C[t][d] ----
#pragma unroll
      for (int i = 0; i < 4; ++i) wb[i] = frag_read64(Ws_q, wnw + i * 16 + fr, kk, quad);
#pragma unroll
      for (int mi = 0; mi < 4; ++mi)
#pragma unroll
        for (int ni = 0; ni < 4; ++ni)
          accq[mi][ni] = __builtin_amdgcn_mfma_f32_16x16x32_bf16(xa[mi], wb[ni], accq[mi][ni], 0, 0, 0);
      // ---- K: C[d][s] ----
#pragma unroll
      for (int i = 0; i < 4; ++i) wb[i] = frag_read64(Ws_k, wnw + i * 16 + fr, kk, quad);
#pragma unroll
      for (int ni = 0; ni < 4; ++ni)
#pragma unroll
        for (int mi = 0; mi < 4; ++mi)
          acck[ni][mi] = __builtin_amdgcn_mfma_f32_16x16x32_bf16(wb[ni], xa[mi], acck[ni][mi], 0, 0, 0);
      // ---- V: C[d][s] ----
#pragma unroll
      for (int i = 0; i < 4; ++i) wb[i] = frag_read64(Ws_v, wnw + i * 16 + fr, kk, quad);
#pragma unroll
      for (int ni = 0; ni < 4; ++ni)
#pragma unroll
        for (int mi = 0; mi < 4; ++mi)
          accv[ni][mi] = __builtin_amdgcn_mfma_f32_16x16x32_bf16(wb[ni], xa[mi], accv[ni][mi], 0, 0, 0);
    }
    __syncthreads();
  }
  // ---- Q epilogue: out = sigmoid(q + bq), f32 ----
#pragma unroll
  for (int mi = 0; mi < 4; ++mi)
#pragma unroll
    for (int ni = 0; ni < 4; ++ni) {
      const int col = n0 + wnw + ni * 16 + fr;
      const float bqv = bq[col];
#pragma unroll
      for (int r = 0; r < 4; ++r) {
        const int row = m0 + wmx + mi * 16 + quad * 4 + r;
        const float qv = accq[mi][ni][r] + bqv;
        out[(size_t)row * 512 + col] = 1.0f / (1.0f + __expf(-qv));
      }
    }
  // ---- KV epilogue: ekT/ekvT [b][d][s] bf16 ----
#pragma unroll
  for (int ni = 0; ni < 4; ++ni)
#pragma unroll
    for (int r = 0; r < 4; ++r) {
      const int d = n0 + wnw + ni * 16 + quad * 4 + r;
      const float bkv = bk[d], bvv = bv[d];
#pragma unroll
      for (int mi = 0; mi < 4; ++mi) {
        const int s = s0 + wmx + mi * 16 + fr;
        const float ek = __expf(acck[ni][mi][r] + bkv);
        const float vvv = accv[ni][mi][r] + bvv;
        const size_t idx = ((size_t)b * 512 + d) * 1024 + s;
        ekT[idx]  = f2bf(ek);
        ekvT[idx] = f2bf(ek * vvv);
      }
    }
}

// ---------- AFT mixing: out = sigq * (EW@ekv) / (EW@ek), per batch ----------
// Proven R0 structure (74.6 us, MfmaUtil 37.9 = the 128^2/2-barrier
// structural ceiling, 921 TF): 128x128 tile, 2-barrier K-loop, ~3 blocks/CU
// implicit overlap. 4-phase lockstep variants measured WORSE (80-83 us,
// R2/R3) - reproduces m232's 128^2+8ph null; 256^2 (the quadrant where
// 8-phase pays) is impossible here: dual num/den acc alone needs 256 VGPRs.
__global__ __launch_bounds__(256, 2) void aft_kernel(const u16* __restrict__ ew,
                                                     const u16* __restrict__ ekT,
                                                     const u16* __restrict__ ekvT,
                                                     float* __restrict__ out) {
  __shared__ __align__(16) u16 As[128 * 64];
  __shared__ __align__(16) u16 B1[128 * 64];
  __shared__ __align__(16) u16 B2[128 * 64];
  const int tid = threadIdx.x;
  const int lane = tid & 63, wv = tid >> 6;
  const int wm = (wv & 1) * 64, wn = (wv >> 1) * 64;
  const int fr = lane & 15, quad = lane >> 4;
  const int d0 = blockIdx.x * 128;   // n: feature dim (512)
  const int t0 = blockIdx.y * 128;   // m: target pos (1024)
  const int b  = blockIdx.z;
  f32x4 accn[4][4] = {}, accd[4][4] = {};
  for (int k0 = 0; k0 < 1024; k0 += 64) {
    stage_tile64(ew + (size_t)t0 * 1024 + k0, 1024, As, tid);
    stage_tile64(ekvT + ((size_t)b * 512 + d0) * 1024 + k0, 1024, B1, tid);
    stage_tile64(ekT + ((size_t)b * 512 + d0) * 1024 + k0, 1024, B2, tid);
    __syncthreads();
#pragma unroll
    for (int kk = 0; kk < 2; ++kk) {
      frag8 a[4], b1[4], b2[4];
#pragma unroll
      for (int i = 0; i < 4; ++i) {
        a[i]  = frag_read64(As, wm + i * 16 + fr, kk, quad);
        b1[i] = frag_read64(B1, wn + i * 16 + fr, kk, quad);
        b2[i] = frag_read64(B2, wn + i * 16 + fr, kk, quad);
      }
#pragma unroll
      for (int mi = 0; mi < 4; ++mi)
#pragma unroll
        for (int ni = 0; ni < 4; ++ni) {
          accn[mi][ni] = __builtin_amdgcn_mfma_f32_16x16x32_bf16(a[mi], b1[ni], accn[mi][ni], 0, 0, 0);
          accd[mi][ni] = __builtin_amdgcn_mfma_f32_16x16x32_bf16(a[mi], b2[ni], accd[mi][ni], 0, 0, 0);
        }
    }
    __syncthreads();
  }
#pragma unroll
  for (int mi = 0; mi < 4; ++mi)
#pragma unroll
    for (int ni = 0; ni < 4; ++ni)
#pragma unroll
      for (int r = 0; r < 4; ++r) {
        const int t = t0 + wm + mi * 16 + quad * 4 + r;
        const int d = d0 + wn + ni * 16 + fr;
        const size_t idx = ((size_t)b * 1024 + t) * 512 + d;
        const float sq = out[idx];                    // sigmoid(q) from qkvu_kernel
        out[idx] = sq * accn[mi][ni][r] / accd[mi][ni][r];
      }
}

// ---------- launch ----------
// Workspace layout (bytes):
//   xb   bf16[32768][512]      @ 0          (32 MB)
//   wqb  bf16[512][512]        @ 33554432
//   wkb                        @ 34078720
//   wvb                        @ 34603008
//   ewb  bf16[1024][1024]      @ 35127296   (2 MB)
//   ekT  bf16[32][512][1024]   @ 37224448   (32 MB)
//   ekvT bf16[32][512][1024]   @ 70778880   (32 MB)
// total ~= 99.5 MB. sigmoid(q) lives in d_out (read-then-overwrite in aft_kernel).
extern "C" void kernel_launch(void* const* d_in, const int* in_sizes, int n_in,
                              void* d_out, int out_size, void* d_ws, size_t ws_size,
                              hipStream_t stream) {
  const float* x  = (const float*)d_in[0];
  const float* Wq = (const float*)d_in[1];
  const float* bq = (const float*)d_in[2];
  const float* Wk = (const float*)d_in[3];
  const float* bk = (const float*)d_in[4];
  const float* Wv = (const float*)d_in[5];
  const float* bv = (const float*)d_in[6];
  const float* pb = (const float*)d_in[7];
  float* out = (float*)d_out;
  char* ws = (char*)d_ws;
  u16* xb   = (u16*)(ws);
  u16* wqb  = (u16*)(ws + 33554432);
  u16* wkb  = (u16*)(ws + 34078720);
  u16* wvb  = (u16*)(ws + 34603008);
  u16* ewb  = (u16*)(ws + 35127296);
  u16* ekT  = (u16*)(ws + 37224448);
  u16* ekvT = (u16*)(ws + 70778880);

  prep_kernel<<<4544, 256, 0, stream>>>(x, Wq, Wk, Wv, pb, xb, wqb, wkb, wvb, ewb);
  qkvu_kernel<<<1024, 256, 0, stream>>>(xb, wqb, wkb, wvb, bq, bk, bv, out, ekT, ekvT);
  aft_kernel<<<dim3(4, 8, 32), 256, 0, stream>>>(ewb, ekT, ekvT, out);
}